// Round 12
// baseline (4546.384 us; speedup 1.0000x reference)
//
#include <hip/hip_runtime.h>
#include <math.h>

#define NB     262144   // batch (tokens)
#define DD     512      // d_routing
#define NG     4        // groups
#define NGS    4        // group size
#define NOUT   20       // 4 group logits + 16 in-group logits

#define TPB    128      // 2 waves/block (the only TPB where dbuf ran clean: R7)
#define TOKS   128      // tokens per block (1 per thread)
#define CH     32       // floats of D per chunk per token (one full 128B line)
#define NCHUNK 16       // DD / CH
#define GRP    260      // 8 tokens * 32 floats + 4 pad floats (proven layout)
#define NXG    16       // staging groups per chunk (TOKS/8)
#define WROWS  24       // 20 weight rows padded to 24 (3 full instructions)

typedef float f32x4 __attribute__((ext_vector_type(4)));

// LDS dest: wave-uniform base + lane*16B, linear, compile-time buffer symbol
// (R6 lesson: runtime-selected dests are catastrophic).
#define GLOAD_LDS16(gsrc, ldst)                                                \
    __builtin_amdgcn_global_load_lds(                                          \
        (const __attribute__((address_space(1))) unsigned int*)(gsrc),         \
        (__attribute__((address_space(3))) unsigned int*)(ldst), 16, 0, 0)

// Stage x chunk into static buffer XB: 8 instr/wave (wave wid owns groups
// wid*8..wid*8+7); each instr = 8 tokens x one full 128B line -> 1KB linear.
#define STAGE_X(ch, XB) do {                                                   \
    const int dd_ = (ch) * CH;                                                 \
    _Pragma("unroll")                                                          \
    for (int kk = 0; kk < 8; ++kk) {                                           \
        const int k_ = wid * 8 + kk;                                           \
        const float* src_ =                                                    \
            x + (size_t)(tok0 + k_ * 8 + lrow) * DD + dd_ + lcol;              \
        GLOAD_LDS16(src_, &XB[k_ * GRP]);                                      \
    }                                                                          \
} while (0)

// Stage w chunk (24 rows x 32 floats, clamp-dup pads): wave 0, 3 instructions.
#define STAGE_W(ch, WB) do {                                                   \
    const int dd_ = (ch) * CH;                                                 \
    if (wid == 0) {                                                            \
        _Pragma("unroll")                                                      \
        for (int m = 0; m < 3; ++m)                                            \
            GLOAD_LDS16(wrow[m] + dd_ + lcol, &WB[m * 8 * CH]);                \
    }                                                                          \
} while (0)

#define COMPUTE(XB, WB) do {                                                   \
    _Pragma("unroll")                                                          \
    for (int g = 0; g < 8; ++g) {                                              \
        const f32x4 xv = *(const f32x4*)&XB[xoff + g * 4];                     \
        _Pragma("unroll")                                                      \
        for (int o = 0; o < NOUT; ++o) {                                       \
            const f32x4 w = *(const f32x4*)&WB[o * CH + g * 4];                \
            float a = acc[o];                                                  \
            a = fmaf(xv.x, w.x, a);                                            \
            a = fmaf(xv.y, w.y, a);                                            \
            a = fmaf(xv.z, w.z, a);                                            \
            a = fmaf(xv.w, w.w, a);                                            \
            acc[o] = a;                                                        \
        }                                                                      \
    }                                                                          \
} while (0)

// R7's proven dbuf skeleton (the only clean dbuf: TPB=128, static buffers,
// STAGE(next) -> COMPUTE(cur) -> __syncthreads), re-geometried for occupancy:
// 39.4KB LDS -> 4 blocks/CU = 8 waves/CU, 4 independent barrier domains.
// Prefetched loads land during the compute phase; the vmcnt(0) drain at each
// __syncthreads is then cheap, and the 4 offset domains keep HBM streaming.
__global__ __launch_bounds__(TPB, 2) void router_k(
    const float* __restrict__ x,        // [NB, DD]
    const float* __restrict__ group_w,  // [NG, DD]
    const float* __restrict__ group_b,  // [NG]
    const float* __restrict__ in_w,     // [NG*NGS, DD]
    const float* __restrict__ in_b,     // [NG, NGS]
    const int*   __restrict__ experts,  // [NG, NGS]
    float*       __restrict__ out)      // [2*NB*2]: indices then weights, fp32
{
    __shared__ float xbA[NXG * GRP];    // 16640 B
    __shared__ float xbB[NXG * GRP];    // 16640 B
    __shared__ float wbA[WROWS * CH];   //  3072 B
    __shared__ float wbB[WROWS * CH];   //  3072 B

    const int tid  = threadIdx.x;
    const int wid  = tid >> 6;          // 0..1
    const int lane = tid & 63;
    const int tok0 = blockIdx.x * TOKS;

    const int lrow = lane >> 3;         // token-in-group for staging
    const int lcol = (lane & 7) * 4;    // float offset within 128B line

    // Weight source rows for the 3 staging instructions (clamp-dup pads).
    const float* wrow[3];
#pragma unroll
    for (int m = 0; m < 3; ++m) {
        int R = m * 8 + lrow;
        if (R > 19) R = 19;
        wrow[m] = (R < NG) ? (group_w + (size_t)R * DD)
                           : (in_w + (size_t)(R - NG) * DD);
    }

    // This thread's token slot inside a buffer (token tid of the block).
    const int xoff = (tid >> 3) * GRP + (tid & 7) * CH;

    float acc[NOUT];
#pragma unroll
    for (int o = 0; o < NOUT; ++o) acc[o] = 0.f;

    STAGE_X(0, xbA);
    STAGE_W(0, wbA);
    __syncthreads();   // buf A ready

#pragma unroll 1
    for (int it = 0; it < 8; ++it) {
        const int ch = 2 * it;

        STAGE_X(ch + 1, xbB);            // transfer overlaps compute(A)
        STAGE_W(ch + 1, wbB);
        COMPUTE(xbA, wbA);
        __syncthreads();                 // B landed; all readers done with A

        if (ch + 2 < NCHUNK) { STAGE_X(ch + 2, xbA); STAGE_W(ch + 2, wbA); }
        COMPUTE(xbB, wbB);
        if (ch + 2 < NCHUNK) __syncthreads();  // A landed; done reading B
    }

    // ---- epilogue (one token per thread) ----
    const int t = tok0 + tid;

    // group argmax (first-max tie-break, matches jnp.argmax)
    float gl[NG];
#pragma unroll
    for (int g = 0; g < NG; ++g) gl[g] = acc[g] + group_b[g];
    int bg = 0;
    float bv = gl[0];
#pragma unroll
    for (int g = 1; g < NG; ++g)
        if (gl[g] > bv) { bv = gl[g]; bg = g; }

    // select chosen group's in-logits without runtime indexing
    float il[NGS];
#pragma unroll
    for (int k = 0; k < NGS; ++k) il[k] = 0.f;
#pragma unroll
    for (int g = 0; g < NG; ++g) {
        const bool sel = (g == bg);
#pragma unroll
        for (int k = 0; k < NGS; ++k)
            il[k] = sel ? acc[NG + g * NGS + k] : il[k];
    }
#pragma unroll
    for (int k = 0; k < NGS; ++k) il[k] += in_b[bg * NGS + k];

    // softmax (fp32, subtract-max)
    float m = fmaxf(fmaxf(il[0], il[1]), fmaxf(il[2], il[3]));
    float p[NGS];
    float s = 0.f;
#pragma unroll
    for (int k = 0; k < NGS; ++k) { p[k] = expf(il[k] - m); s += p[k]; }
    const float inv = 1.0f / s;
#pragma unroll
    for (int k = 0; k < NGS; ++k) p[k] *= inv;

    // top-2 (descending, lower-index-on-tie, matches lax.top_k)
    int i1 = 0;
    float v1 = p[0];
#pragma unroll
    for (int k = 1; k < NGS; ++k)
        if (p[k] > v1) { v1 = p[k]; i1 = k; }
    int i2 = -1;
    float v2 = -3.0e38f;
#pragma unroll
    for (int k = 0; k < NGS; ++k)
        if (k != i1 && p[k] > v2) { v2 = p[k]; i2 = k; }

    const int id1 = experts[bg * NGS + i1];
    const int id2 = experts[bg * NGS + i2];

    float2* outi = reinterpret_cast<float2*>(out);
    float2* outw = reinterpret_cast<float2*>(out + (size_t)NB * 2);
    outi[t] = make_float2((float)id1, (float)id2);
    outw[t] = make_float2(v1, v2);
}

extern "C" void kernel_launch(void* const* d_in, const int* in_sizes, int n_in,
                              void* d_out, int out_size, void* d_ws, size_t ws_size,
                              hipStream_t stream) {
    const float* x  = (const float*)d_in[0];
    const float* gw = (const float*)d_in[1];
    const float* gb = (const float*)d_in[2];
    const float* iw = (const float*)d_in[3];
    const float* ib = (const float*)d_in[4];
    const int*   et = (const int*)d_in[5];
    float* out = (float*)d_out;

    router_k<<<dim3(NB / TOKS), dim3(TPB), 0, stream>>>(x, gw, gb, iw, ib, et, out);
}

// Round 13
// 4241.287 us; speedup vs baseline: 1.0719x; 1.0719x over previous
//
#include <hip/hip_runtime.h>
#include <math.h>

#define NB     262144   // batch (tokens)
#define DD     512      // d_routing
#define NG     4        // groups
#define NGS    4        // group size
#define NOUT   20       // 4 group logits + 16 in-group logits

#define TPB    256      // 4 waves/block
#define TOKS   256      // tokens per block (1 per thread)
#define CH     16       // floats of D per chunk per token (64B)
#define NCHUNK 32       // DD / CH
#define SGRP   260      // 16 tokens * 16 floats + 4 pad floats (bank spread)
#define NSG    16       // staging groups per chunk (TOKS/16)

typedef float f32x4 __attribute__((ext_vector_type(4)));

// NO global_load_lds anywhere (banned: R6/R8/R9/R12 all broke with it in any
// prefetch-while-compute shape). Register staging instead: global_load ->
// named VGPR sets -> ds_write. Plain instructions only.

// Issue the 4 coalesced x loads for chunk `ch` into one named reg set.
// Instr m: 16 tokens x 64B segments (every byte consumed; L2 merges halves).
#define LOAD_X(ch, R0, R1, R2, R3) do {                                        \
    R0 = *(const f32x4*)(xsrc0 + (ch) * CH);                                   \
    R1 = *(const f32x4*)(xsrc1 + (ch) * CH);                                   \
    R2 = *(const f32x4*)(xsrc2 + (ch) * CH);                                   \
    R3 = *(const f32x4*)(xsrc3 + (ch) * CH);                                   \
} while (0)

#define LOAD_W(ch, W0, W1) do {                                                \
    if (wid == 0) {                                                            \
        W0 = *(const f32x4*)(wsrc0 + (ch) * CH);                               \
        W1 = *(const f32x4*)(wsrc1 + (ch) * CH);                               \
    }                                                                          \
} while (0)

#define DSW_X(R0, R1, R2, R3) do {                                             \
    *(f32x4*)&xb[ldw0] = R0;                                                   \
    *(f32x4*)&xb[ldw1] = R1;                                                   \
    *(f32x4*)&xb[ldw2] = R2;                                                   \
    *(f32x4*)&xb[ldw3] = R3;                                                   \
} while (0)

#define DSW_W(W0, W1) do {                                                     \
    if (wid == 0) {                                                            \
        *(f32x4*)&wb[wld0] = W0;                                               \
        *(f32x4*)&wb[wld1] = W1;                                               \
    }                                                                          \
} while (0)

#define COMPUTE() do {                                                         \
    _Pragma("unroll")                                                          \
    for (int g = 0; g < 4; ++g) {                                              \
        const f32x4 xv = *(const f32x4*)&xb[xoff + g * 4];                     \
        _Pragma("unroll")                                                      \
        for (int o = 0; o < NOUT; ++o) {                                       \
            const f32x4 wv = *(const f32x4*)&wb[o * CH + g * 4];               \
            float a = acc[o];                                                  \
            a = fmaf(xv.x, wv.x, a);                                           \
            a = fmaf(xv.y, wv.y, a);                                           \
            a = fmaf(xv.z, wv.z, a);                                           \
            a = fmaf(xv.w, wv.w, a);                                           \
            acc[o] = a;                                                        \
        }                                                                      \
    }                                                                          \
} while (0)

__global__ __launch_bounds__(TPB, 4) void router_k(
    const float* __restrict__ x,        // [NB, DD]
    const float* __restrict__ group_w,  // [NG, DD]
    const float* __restrict__ group_b,  // [NG]
    const float* __restrict__ in_w,     // [NG*NGS, DD]
    const float* __restrict__ in_b,     // [NG, NGS]
    const int*   __restrict__ experts,  // [NG, NGS]
    float*       __restrict__ out)      // [2*NB*2]: indices then weights, fp32
{
    __shared__ float xb[NSG * SGRP];    // 16640 B (single chunk; dbuf is in regs)
    __shared__ float wb[32 * CH];       //  2048 B (32 rows x 16 floats)

    const int tid  = threadIdx.x;
    const int wid  = tid >> 6;          // 0..3
    const int lane = tid & 63;
    const int tok0 = blockIdx.x * TOKS;

    const int srow = lane >> 2;         // token-in-sgroup (0..15)
    const int scol = (lane & 3) * 4;    // float offset within 64B segment

    // x staging sources: instr m covers sgroup wid*4+m (16 tokens x 64B).
    const float* xsrc0 = x + (size_t)(tok0 + (wid * 4 + 0) * 16 + srow) * DD + scol;
    const float* xsrc1 = x + (size_t)(tok0 + (wid * 4 + 1) * 16 + srow) * DD + scol;
    const float* xsrc2 = x + (size_t)(tok0 + (wid * 4 + 2) * 16 + srow) * DD + scol;
    const float* xsrc3 = x + (size_t)(tok0 + (wid * 4 + 3) * 16 + srow) * DD + scol;

    // LDS write offsets (dwords; 16B aligned).
    const int ldw0 = (wid * 4 + 0) * SGRP + srow * CH + (lane & 3) * 4;
    const int ldw1 = (wid * 4 + 1) * SGRP + srow * CH + (lane & 3) * 4;
    const int ldw2 = (wid * 4 + 2) * SGRP + srow * CH + (lane & 3) * 4;
    const int ldw3 = (wid * 4 + 3) * SGRP + srow * CH + (lane & 3) * 4;

    // w staging (wave 0): instr0 rows 0..15, instr1 rows 16..31 (clamp-dup 19).
    const int r0 = lane >> 2;
    int r1 = 16 + (lane >> 2);
    if (r1 > 19) r1 = 19;
    const float* wsrc0 = ((r0 < NG) ? (group_w + (size_t)r0 * DD)
                                    : (in_w + (size_t)(r0 - NG) * DD)) + scol;
    const float* wsrc1 = (in_w + (size_t)(r1 - NG) * DD) + scol;
    const int wld0 = r0 * CH + (lane & 3) * 4;
    const int wld1 = (16 + (lane >> 2)) * CH + (lane & 3) * 4;

    // Compute-side: this thread's token slot.
    const int xoff = (tid >> 4) * SGRP + (tid & 15) * CH;

    float acc[NOUT];
#pragma unroll
    for (int o = 0; o < NOUT; ++o) acc[o] = 0.f;

    f32x4 xa0, xa1, xa2, xa3, xb0, xb1, xb2, xb3;   // two named stage sets
    f32x4 wa0, wa1, wb0_, wb1_;

    // ---- prologue: chunk 0 -> LDS; chunk 1 -> regs (in flight) ----
    LOAD_X(0, xa0, xa1, xa2, xa3);
    LOAD_W(0, wa0, wa1);
    DSW_X(xa0, xa1, xa2, xa3);          // compiler waits vmcnt as needed
    DSW_W(wa0, wa1);
    LOAD_X(1, xb0, xb1, xb2, xb3);      // chunk 1 rides during compute(0)
    LOAD_W(1, wb0_, wb1_);
    __syncthreads();                    // chunk 0 visible

#pragma unroll 1
    for (int it = 0; it < 15; ++it) {
        const int c = 2 * it;
        COMPUTE();                      // chunk c
        __syncthreads();                // all readers done
        DSW_X(xb0, xb1, xb2, xb3);      // write c+1
        DSW_W(wb0_, wb1_);
        LOAD_X(c + 2, xa0, xa1, xa2, xa3);   // issue c+2 (lands during compute)
        LOAD_W(c + 2, wa0, wa1);
        __syncthreads();                // c+1 visible
        COMPUTE();                      // chunk c+1
        __syncthreads();
        DSW_X(xa0, xa1, xa2, xa3);      // write c+2
        DSW_W(wa0, wa1);
        LOAD_X(c + 3, xb0, xb1, xb2, xb3);   // issue c+3
        LOAD_W(c + 3, wb0_, wb1_);
        __syncthreads();                // c+2 visible
    }
    // After loop: chunks 0..29 computed, chunk 30 in LDS, chunk 31 in xb regs.
    COMPUTE();                          // chunk 30
    __syncthreads();
    DSW_X(xb0, xb1, xb2, xb3);          // write 31
    DSW_W(wb0_, wb1_);
    __syncthreads();
    COMPUTE();                          // chunk 31

    // ---- epilogue (one token per thread; identical to R11) ----
    const int t = tok0 + tid;

    float gl[NG];
#pragma unroll
    for (int g = 0; g < NG; ++g) gl[g] = acc[g] + group_b[g];
    int bg = 0;
    float bv = gl[0];
#pragma unroll
    for (int g = 1; g < NG; ++g)
        if (gl[g] > bv) { bv = gl[g]; bg = g; }

    float il[NGS];
#pragma unroll
    for (int k = 0; k < NGS; ++k) il[k] = 0.f;
#pragma unroll
    for (int g = 0; g < NG; ++g) {
        const bool sel = (g == bg);
#pragma unroll
        for (int k = 0; k < NGS; ++k)
            il[k] = sel ? acc[NG + g * NGS + k] : il[k];
    }
#pragma unroll
    for (int k = 0; k < NGS; ++k) il[k] += in_b[bg * NGS + k];

    float m = fmaxf(fmaxf(il[0], il[1]), fmaxf(il[2], il[3]));
    float p[NGS];
    float s = 0.f;
#pragma unroll
    for (int k = 0; k < NGS; ++k) { p[k] = expf(il[k] - m); s += p[k]; }
    const float inv = 1.0f / s;
#pragma unroll
    for (int k = 0; k < NGS; ++k) p[k] *= inv;

    int i1 = 0;
    float v1 = p[0];
#pragma unroll
    for (int k = 1; k < NGS; ++k)
        if (p[k] > v1) { v1 = p[k]; i1 = k; }
    int i2 = -1;
    float v2 = -3.0e38f;
#pragma unroll
    for (int k = 0; k < NGS; ++k)
        if (k != i1 && p[k] > v2) { v2 = p[k]; i2 = k; }

    const int id1 = experts[bg * NGS + i1];
    const int id2 = experts[bg * NGS + i2];

    float2* outi = reinterpret_cast<float2*>(out);
    float2* outw = reinterpret_cast<float2*>(out + (size_t)NB * 2);
    outi[t] = make_float2((float)id1, (float)id2);
    outw[t] = make_float2(v1, v2);
}

extern "C" void kernel_launch(void* const* d_in, const int* in_sizes, int n_in,
                              void* d_out, int out_size, void* d_ws, size_t ws_size,
                              hipStream_t stream) {
    const float* x  = (const float*)d_in[0];
    const float* gw = (const float*)d_in[1];
    const float* gb = (const float*)d_in[2];
    const float* iw = (const float*)d_in[3];
    const float* ib = (const float*)d_in[4];
    const int*   et = (const int*)d_in[5];
    float* out = (float*)d_out;

    router_k<<<dim3(NB / TOKS), dim3(TPB), 0, stream>>>(x, gw, gb, iw, ib, et, out);
}

// Round 14
// 175.177 us; speedup vs baseline: 25.9531x; 24.2114x over previous
//
#include <hip/hip_runtime.h>
#include <math.h>

#define NB     262144   // batch (tokens)
#define DD     512      // d_routing
#define NG     4        // groups
#define NGS    4        // group size
#define NOUT   20       // 4 group logits + 16 in-group logits

#define TPB    256      // threads per block (4 waves)
#define TOKS   256      // tokens per block (1 per thread)
#define CH     32       // floats of D per chunk per token (one full 128B line)
#define NCHUNK 16       // DD / CH
#define GRP    260      // 8 tokens * 32 floats + 4 pad floats (proven layout)
#define NXG    32       // staging groups per chunk (TOKS/8)
#define WROWS  24       // 20 weight rows padded to 24 (3 full instructions)

typedef float f32x4 __attribute__((ext_vector_type(4)));

// Proven-clean R5/R11 schedule, tile halved: 36,352B LDS -> 4 blocks/CU =
// 16 waves/CU, 4 independently-phased barrier domains. Single buffer,
// stage -> sync -> compute -> sync. No prefetch-in-flight across compute
// (every pipelined variant -- R6/R8/R9/R12/R13 -- hit a toolchain pathology).
#define GLOAD_LDS16(gsrc, ldst)                                                \
    __builtin_amdgcn_global_load_lds(                                          \
        (const __attribute__((address_space(1))) unsigned int*)(gsrc),         \
        (__attribute__((address_space(3))) unsigned int*)(ldst), 16, 0, 0)

__global__ __launch_bounds__(TPB, 4) void router_k(
    const float* __restrict__ x,        // [NB, DD]
    const float* __restrict__ group_w,  // [NG, DD]
    const float* __restrict__ group_b,  // [NG]
    const float* __restrict__ in_w,     // [NG*NGS, DD]
    const float* __restrict__ in_b,     // [NG, NGS]
    const int*   __restrict__ experts,  // [NG, NGS]
    float*       __restrict__ out)      // [2*NB*2]: indices then weights, fp32
{
    __shared__ float xbuf[NXG * GRP];   // 33280 B
    __shared__ float wbuf[WROWS * CH];  //  3072 B

    const int tid  = threadIdx.x;
    const int wid  = tid >> 6;          // 0..3
    const int lane = tid & 63;
    const int tok0 = blockIdx.x * TOKS;

    const int lrow = lane >> 3;         // token-in-group for staging
    const int lcol = (lane & 7) * 4;    // float offset within 128B line

    // Weight source rows for the 3 staging instructions (clamp-dup pads).
    const float* wrow[3];
#pragma unroll
    for (int m = 0; m < 3; ++m) {
        int R = m * 8 + lrow;
        if (R > 19) R = 19;
        wrow[m] = (R < NG) ? (group_w + (size_t)R * DD)
                           : (in_w + (size_t)(R - NG) * DD);
    }

    // This thread's token slot inside the buffer (token tid of the block).
    const int xoff = (tid >> 3) * GRP + (tid & 7) * CH;

    float acc[NOUT];
#pragma unroll
    for (int o = 0; o < NOUT; ++o) acc[o] = 0.f;

#pragma unroll 1
    for (int ch = 0; ch < NCHUNK; ++ch) {
        const int dd = ch * CH;

        // ---- stage x chunk: wave wid issues groups k = wid*8 .. wid*8+7.
        // Each instr: 8 tokens x one full 128B line -> 1KB linear LDS dest.
#pragma unroll
        for (int kk = 0; kk < 8; ++kk) {
            const int k = wid * 8 + kk;
            const float* src =
                x + (size_t)(tok0 + k * 8 + lrow) * DD + dd + lcol;
            GLOAD_LDS16(src, &xbuf[k * GRP]);
        }

        // ---- stage w chunk (24 rows x 32 floats): wave 0, 3 instructions.
        if (wid == 0) {
#pragma unroll
            for (int m = 0; m < 3; ++m)
                GLOAD_LDS16(wrow[m] + dd + lcol, &wbuf[m * 8 * CH]);
        }

        __syncthreads();   // vmcnt(0) drain + barrier: chunk ready

        // ---- compute: per granule g, 1 x-read + 20 w-broadcasts.
#pragma unroll
        for (int g = 0; g < 8; ++g) {
            const f32x4 xv = *(const f32x4*)&xbuf[xoff + g * 4];
#pragma unroll
            for (int o = 0; o < NOUT; ++o) {
                const f32x4 w = *(const f32x4*)&wbuf[o * CH + g * 4];
                float a = acc[o];
                a = fmaf(xv.x, w.x, a);
                a = fmaf(xv.y, w.y, a);
                a = fmaf(xv.z, w.z, a);
                a = fmaf(xv.w, w.w, a);
                acc[o] = a;
            }
        }

        __syncthreads();   // all reads done before next chunk overwrites
    }

    // ---- epilogue (one token per thread; proven path) ----
    const int t = tok0 + tid;

    // group argmax (first-max tie-break, matches jnp.argmax)
    float gl[NG];
#pragma unroll
    for (int g = 0; g < NG; ++g) gl[g] = acc[g] + group_b[g];
    int bg = 0;
    float bv = gl[0];
#pragma unroll
    for (int g = 1; g < NG; ++g)
        if (gl[g] > bv) { bv = gl[g]; bg = g; }

    // select chosen group's in-logits without runtime indexing
    float il[NGS];
#pragma unroll
    for (int k = 0; k < NGS; ++k) il[k] = 0.f;
#pragma unroll
    for (int g = 0; g < NG; ++g) {
        const bool sel = (g == bg);
#pragma unroll
        for (int k = 0; k < NGS; ++k)
            il[k] = sel ? acc[NG + g * NGS + k] : il[k];
    }
#pragma unroll
    for (int k = 0; k < NGS; ++k) il[k] += in_b[bg * NGS + k];

    // softmax (fp32, subtract-max)
    float m = fmaxf(fmaxf(il[0], il[1]), fmaxf(il[2], il[3]));
    float p[NGS];
    float s = 0.f;
#pragma unroll
    for (int k = 0; k < NGS; ++k) { p[k] = expf(il[k] - m); s += p[k]; }
    const float inv = 1.0f / s;
#pragma unroll
    for (int k = 0; k < NGS; ++k) p[k] *= inv;

    // top-2 (descending, lower-index-on-tie, matches lax.top_k)
    int i1 = 0;
    float v1 = p[0];
#pragma unroll
    for (int k = 1; k < NGS; ++k)
        if (p[k] > v1) { v1 = p[k]; i1 = k; }
    int i2 = -1;
    float v2 = -3.0e38f;
#pragma unroll
    for (int k = 0; k < NGS; ++k)
        if (k != i1 && p[k] > v2) { v2 = p[k]; i2 = k; }

    const int id1 = experts[bg * NGS + i1];
    const int id2 = experts[bg * NGS + i2];

    float2* outi = reinterpret_cast<float2*>(out);
    float2* outw = reinterpret_cast<float2*>(out + (size_t)NB * 2);
    outi[t] = make_float2((float)id1, (float)id2);
    outw[t] = make_float2(v1, v2);
}

extern "C" void kernel_launch(void* const* d_in, const int* in_sizes, int n_in,
                              void* d_out, int out_size, void* d_ws, size_t ws_size,
                              hipStream_t stream) {
    const float* x  = (const float*)d_in[0];
    const float* gw = (const float*)d_in[1];
    const float* gb = (const float*)d_in[2];
    const float* iw = (const float*)d_in[3];
    const float* ib = (const float*)d_in[4];
    const int*   et = (const int*)d_in[5];
    float* out = (float*)d_out;

    router_k<<<dim3(NB / TOKS), dim3(TPB), 0, stream>>>(x, gw, gb, iw, ib, et, out);
}